// Round 2
// baseline (8223.021 us; speedup 1.0000x reference)
//
#include <hip/hip_runtime.h>
#include <hip/hip_bf16.h>

#define HID   256
#define BATCH 2048
#define NGATE 1024
#define NCLU  64      // batch-slice clusters
#define NMEM  4       // WGs per cluster (unit groups)
#define BM    32      // batch rows per cluster
#define UG    64      // hidden units per member
#define TPB   256     // 4 waves, 1 per SIMD

typedef __attribute__((ext_vector_type(8))) short bf16x8;
typedef __attribute__((ext_vector_type(8))) unsigned short u16x8;
typedef __attribute__((ext_vector_type(4))) float f32x4;

__device__ __forceinline__ unsigned short f2bf(float x){
  unsigned int u = __builtin_bit_cast(unsigned int, x);
  u += 0x7fffu + ((u >> 16) & 1u);          // RNE
  return (unsigned short)(u >> 16);
}
__device__ __forceinline__ float fsigm(float x){
  return __builtin_amdgcn_rcpf(1.0f + __expf(-x));
}
__device__ __forceinline__ float ftanh_(float x){
  return fmaf(2.0f, __builtin_amdgcn_rcpf(1.0f + __expf(-2.0f*x)), -1.0f);
}

// Pack W_ih and (W_ih+W_hh) into MFMA B-fragment order:
// frag(nt,kt) is 1KB, lane-linear: lane l holds W[nt*16 + (l&15)][kt*32 + (l>>4)*8 + j]
__global__ void pack_kernel(const float* __restrict__ Wih, const float* __restrict__ Whh,
                            const float* __restrict__ bih, const float* __restrict__ bhh,
                            unsigned short* __restrict__ Wih_p,
                            unsigned short* __restrict__ Wsum_p,
                            float* __restrict__ bias,
                            int* __restrict__ flags){
  int tid = blockIdx.x * blockDim.x + threadIdx.x;   // 0..262143
  int j  = tid & 7;
  int ln = (tid >> 3) & 63;
  int kt = (tid >> 9) & 7;
  int nt = tid >> 12;
  int n = nt*16 + (ln & 15);
  int k = kt*32 + (ln >> 4)*8 + j;
  float wih = Wih[n*HID + k];
  float whh = Whh[n*HID + k];
  Wih_p[tid]  = f2bf(wih);
  Wsum_p[tid] = f2bf(wih + whh);
  if (tid < NGATE) bias[tid] = bih[tid] + bhh[tid];
  if (tid < NCLU*NMEM) flags[tid] = 0;
}

// 256 WGs: cluster = blockIdx&63 (batch rows [32c,32c+32)), member = blockIdx>>6
// (units [64m, 64m+64)). All weights for the member's 256 gate rows live in
// VGPRs (128 regs/lane). Per-step h exchange among the 4 cluster members via
// global xbuf (parity double-buffered) + monotonic agent-scope flags.
__global__ __launch_bounds__(TPB, 1)
void lstm_kernel(const float* __restrict__ h_in,
                 const unsigned short* __restrict__ Wih_p,
                 const unsigned short* __restrict__ Wsum_p,
                 const float* __restrict__ bias,
                 const int* __restrict__ seqlen,
                 float* __restrict__ out,
                 unsigned short* __restrict__ xbuf,
                 int* __restrict__ flags){
  const int T       = seqlen[0];
  const int cluster = blockIdx.x & (NCLU-1);
  const int member  = blockIdx.x >> 6;
  const int tid     = threadIdx.x;
  const int w   = tid >> 6;       // wave 0..3
  const int l   = tid & 63;
  const int l15 = l & 15;
  const int lq  = l >> 4;

  // h for the current step, A-frag layout: frag(kt,mt) at ushort offset
  // (kt*2+mt)*512; within-frag lane_a*8+j, lane_a = kg*16 + (m&15), k = kt*32+kg*8+j
  __shared__ __align__(16) unsigned short hbuf[8192];   // 16 KB

  // ---- stage t=0 input x (= h_in) into hbuf ----
  for (int p = 0; p < 32; ++p){
    int flat   = tid*32 + p;
    int frag   = flat >> 9, within = flat & 511;
    int lane_a = within >> 3, j = within & 7;
    int kt = frag >> 1, mt = frag & 1;
    int m  = mt*16 + (lane_a & 15);
    int k  = kt*32 + (lane_a >> 4)*8 + j;
    hbuf[flat] = f2bf(h_in[(size_t)(cluster*BM + m)*HID + k]);
  }

  const int u   = member*UG + w*16 + l15;   // my gate column / hidden unit
  const int kg  = (u & 31) >> 3;
  const int ktO = u >> 5;
  const int u7  = u & 7;

  float bv[4];
  #pragma unroll
  for (int ga = 0; ga < 4; ++ga) bv[ga] = bias[ga*HID + u];

  // ---- weights in registers: 4 gates x 8 k-tiles, 4 VGPR each = 128 VGPRs ----
  bf16x8 wreg[4][8];
  #pragma unroll
  for (int ga = 0; ga < 4; ++ga){
    const int nt = ga*16 + member*4 + w;
    #pragma unroll
    for (int kt = 0; kt < 8; ++kt)
      wreg[ga][kt] = *(const bf16x8*)(Wih_p + ((size_t)(nt*8 + kt)*512 + l*8));
  }

  float cs[2][4];
  #pragma unroll
  for (int mt = 0; mt < 2; ++mt)
    #pragma unroll
    for (int r = 0; r < 4; ++r) cs[mt][r] = 0.0f;

  __syncthreads();

  for (int t = 0; t < T; ++t){
    // ---- gates = h @ W^T + b ----
    f32x4 acc[4][2];
    #pragma unroll
    for (int ga = 0; ga < 4; ++ga){
      f32x4 bi = {bv[ga], bv[ga], bv[ga], bv[ga]};
      acc[ga][0] = bi; acc[ga][1] = bi;
    }
    #pragma unroll
    for (int kt = 0; kt < 8; ++kt){
      bf16x8 a0 = *(const bf16x8*)&hbuf[(kt*2 + 0)*512 + l*8];
      bf16x8 a1 = *(const bf16x8*)&hbuf[(kt*2 + 1)*512 + l*8];
      #pragma unroll
      for (int ga = 0; ga < 4; ++ga){
        acc[ga][0] = __builtin_amdgcn_mfma_f32_16x16x32_bf16(a0, wreg[ga][kt], acc[ga][0], 0, 0, 0);
        acc[ga][1] = __builtin_amdgcn_mfma_f32_16x16x32_bf16(a1, wreg[ga][kt], acc[ga][1], 0, 0, 0);
      }
    }
    if (t == 0){
      // t>=1 uses W_ih + W_hh (x and hidden are the same h): swap register set
      #pragma unroll
      for (int ga = 0; ga < 4; ++ga){
        const int nt = ga*16 + member*4 + w;
        #pragma unroll
        for (int kt = 0; kt < 8; ++kt)
          wreg[ga][kt] = *(const bf16x8*)(Wsum_p + ((size_t)(nt*8 + kt)*512 + l*8));
      }
    }
    __syncthreads();   // all hbuf A-reads done; safe to overwrite own region

    // ---- elementwise LSTM update + stores ----
    const int orow = (t == 0) ? 0 : (T - t);
    float* __restrict__ op = out + (size_t)orow * (BATCH*HID);
    const bool last = (t == T - 1);
    u16x8 hp;
    #pragma unroll
    for (int mt = 0; mt < 2; ++mt){
      #pragma unroll
      for (int r = 0; r < 4; ++r){
        const int m  = mt*16 + lq*4 + r;
        const float iv = fsigm (acc[0][mt][r]);
        const float fv = fsigm (acc[1][mt][r]);
        const float gv = ftanh_(acc[2][mt][r]);
        const float ov = fsigm (acc[3][mt][r]);
        const float cn = fv * cs[mt][r] + iv * gv;
        cs[mt][r] = cn;
        const float hv = ov * ftanh_(cn);
        const unsigned short hb = f2bf(hv);
        hp[mt*4 + r] = hb;
        hbuf[(ktO*2 + mt)*512 + (kg*16 + (m & 15))*8 + u7] = hb;   // own A-frag slice
        const size_t gi = (size_t)(cluster*BM + m)*HID + u;
        __builtin_nontemporal_store(hv, op + gi);
        if (last){
          __builtin_nontemporal_store(hv, out + (size_t)T*(BATCH*HID) + gi);       // hf
          __builtin_nontemporal_store(cn, out + (size_t)(T + 1)*(BATCH*HID) + gi); // cf
        }
      }
    }

    if (t < T - 1){
      // ---- publish own h-slice (lane-linear 16B/lane), parity double-buffered ----
      unsigned short* __restrict__ xb =
          xbuf + ((size_t)(t & 1)*NCLU + cluster)*8192;
      *(u16x8*)(xb + member*2048 + tid*8) = hp;
      __syncthreads();                       // drains all waves' stores to L2
      if (tid == 0){
        __builtin_amdgcn_fence(__ATOMIC_RELEASE, "agent");   // L2 writeback
        __hip_atomic_store(&flags[cluster*NMEM + member], t + 1,
                           __ATOMIC_RELAXED, __HIP_MEMORY_SCOPE_AGENT);
      }
      if (tid < 3){
        const int om = tid + (tid >= member ? 1 : 0);
        while (__hip_atomic_load(&flags[cluster*NMEM + om],
                                 __ATOMIC_RELAXED, __HIP_MEMORY_SCOPE_AGENT) <= t) {}
      }
      __syncthreads();
      __builtin_amdgcn_fence(__ATOMIC_ACQUIRE, "agent");     // L1/L2 invalidate
      // ---- fetch the 3 other slices, unpack into hbuf A-frag layout ----
      #pragma unroll
      for (int jj = 0; jj < 3; ++jj){
        const int om  = jj + (jj >= member ? 1 : 0);
        u16x8 v = *(const u16x8*)(xb + om*2048 + tid*8);
        const int uo  = om*UG + (tid >> 6)*16 + (tid & 15);
        const int kgo = (uo & 31) >> 3;
        const int kto = uo >> 5;
        const int uo7 = uo & 7;
        const int lq2 = (tid >> 4) & 3;
        #pragma unroll
        for (int idx = 0; idx < 8; ++idx){
          const int mt = idx >> 2, r = idx & 3;
          hbuf[(kto*2 + mt)*512 + (kgo*16 + lq2*4 + r)*8 + uo7] = v[idx];
        }
      }
      __syncthreads();                       // hbuf ready for next step
    }
  }
}

extern "C" void kernel_launch(void* const* d_in, const int* in_sizes, int n_in,
                              void* d_out, int out_size, void* d_ws, size_t ws_size,
                              hipStream_t stream) {
  const float* h_in = (const float*)d_in[0];
  const float* Wih  = (const float*)d_in[1];
  const float* Whh  = (const float*)d_in[2];
  const float* bih  = (const float*)d_in[3];
  const float* bhh  = (const float*)d_in[4];
  const int*   seq  = (const int*)  d_in[5];
  float* out = (float*)d_out;

  unsigned short* Wih_p  = (unsigned short*)d_ws;                    // 512 KB
  unsigned short* Wsum_p = Wih_p + (size_t)NGATE * HID;              // 512 KB
  float*          bias   = (float*)(Wsum_p + (size_t)NGATE * HID);   // 4 KB
  int*            flags  = (int*)(bias + NGATE);                     // 1 KB
  unsigned short* xbuf   = (unsigned short*)(flags + NCLU*NMEM);     // 2 MB

  pack_kernel<<<dim3((NGATE*HID)/256), dim3(256), 0, stream>>>(
      Wih, Whh, bih, bhh, Wih_p, Wsum_p, bias, flags);

  lstm_kernel<<<dim3(NCLU*NMEM), dim3(TPB), 0, stream>>>(
      h_in, Wih_p, Wsum_p, bias, seq, out, xbuf, flags);
}